// Round 4
// baseline (412.643 us; speedup 1.0000x reference)
//
#include <hip/hip_runtime.h>

#define TPB 256
#define ROWN 8192
#define CMAX 1024   // per-row candidate cap (r12-r18 proven never hit)
#define EPS_TINY 1.1754943508222875e-38f   // np.finfo(np.float32).tiny

__device__ __forceinline__ unsigned rotl32(unsigned x, int r) {
  return (x << r) | (x >> (32 - r));
}

// threefry2x32, key (0,42), partitionable counters: ctr=(0,idx), bits = x0^x1.
__device__ __forceinline__ unsigned tf_pxor(unsigned idx) {
  const unsigned ks0 = 0u, ks1 = 42u, ks2 = 0x1BD11BDAu ^ 0u ^ 42u;
  unsigned x0 = ks0;
  unsigned x1 = idx + ks1;
#define TF4(a,b,cc,d) \
  x0 += x1; x1 = rotl32(x1,(a));  x1 ^= x0; \
  x0 += x1; x1 = rotl32(x1,(b));  x1 ^= x0; \
  x0 += x1; x1 = rotl32(x1,(cc)); x1 ^= x0; \
  x0 += x1; x1 = rotl32(x1,(d));  x1 ^= x0;
  TF4(13,15,26,6)   x0 += ks1; x1 += ks2 + 1u;
  TF4(17,29,16,24)  x0 += ks2; x1 += ks0 + 2u;
  TF4(13,15,26,6)   x0 += ks0; x1 += ks1 + 3u;
  TF4(17,29,16,24)  x0 += ks1; x1 += ks2 + 4u;
  TF4(13,15,26,6)   x0 += ks2; x1 += ks0 + 5u;
#undef TF4
  return x0 ^ x1;
}

// EXACT jax gumbel (precise ocml logf) — candidates only, bit-exact.
__device__ __forceinline__ float gumbel_of(unsigned idx) {
  const unsigned bits = tf_pxor(idx);
  float u = __uint_as_float((bits >> 9) | 0x3f800000u) - 1.0f;
  u = u + EPS_TINY;
  u = fmaxf(EPS_TINY, u);
  return -logf(-logf(u));
}

// APPROX gumbel for the filter pass: |err| <= ~2e-4 (proven r15-r18).
__device__ __forceinline__ float approx_gumbel(unsigned bits) {
  float u = __uint_as_float((bits >> 9) | 0x3f800000u) - 1.0f;
  u = u + EPS_TINY;
  u = fmaxf(EPS_TINY, u);
  float t;
  if (u >= 0.75f) {
    const float v = 1.0f - u;   // exact (Sterbenz)
    t = v * (1.0f + v * (0.5f + v * (0.33333334f + v * (0.25f + v * 0.2f))));
  } else {
    t = -0.69314718f * __log2f(u);
  }
  return -0.69314718f * __log2f(t);
}

// =====================================================================
// Kernel A: gen -> theta -> compact -> exact-cf. One block per row,
// 512 threads (8 waves), f[16]/thread => ~50 live VGPRs <= 64 budget
// at (512,8): NO SPILLS (r1/r3's VGPR=32 + 38MB scratch writes fixed).
// Writes u16 idx + f32 exact cf + cnt per row to workspace.
// =====================================================================
__global__ __launch_bounds__(512, 8)
void gen_compact(const void* __restrict__ scores_raw,
                 unsigned short* __restrict__ idxArr,
                 float* __restrict__ cfArr,
                 int* __restrict__ cntArr) {
  const int t    = threadIdx.x;      // 0..511
  const int lane = t & 63;
  const int wave = t >> 6;           // 0..7

  // XCD grouping: all 8 rows (4e x 2rep) of input panel b land on one XCD.
  const int i   = blockIdx.x;        // 0..2047
  const int xcd = i & 7;
  const int k   = i >> 3;
  const int e   = k & 3;
  const int q   = k >> 2;
  const int b   = xcd * 32 + (q & 31);
  const int rep = q >> 5;
  const int r   = rep * 1024 + b * 4 + e;
  const unsigned gbase = (unsigned)r * (unsigned)ROWN;

  __shared__ float redM[8];
  __shared__ int   wtot[13][8];
  __shared__ int   f32flag;

  // ---- input dtype autodetect (4 KB prefix; proven) ----
  if (t == 0) f32flag = 0;
  __syncthreads();
  {
    const unsigned* w = (const unsigned*)scores_raw;
    bool bad = false;
#pragma unroll
    for (int p = 0; p < 2; ++p) {
      const unsigned x = w[t + 512 * p];
      const float flo = __uint_as_float((x & 0xFFFFu) << 16);
      const float fhi = __uint_as_float(x & 0xFFFF0000u);
      if (!(fabsf(flo) <= 16.0f) || !(fabsf(fhi) <= 16.0f)) bad = true;
    }
    if (bad) f32flag = 1;
  }
  __syncthreads();
  const bool in_f32 = (f32flag != 0);

  // ---- gen: 16 elems/thread, n = t + 512*j (f(n) identical to r1/r3) ----
  const size_t ebase0 = ((size_t)b * ROWN + (size_t)t) * 4 + (size_t)e;
  float f[16];
  if (in_f32) {
    const float* sp = (const float*)scores_raw;
#pragma unroll
    for (int j = 0; j < 16; ++j)
      f[j] = sp[ebase0 + (size_t)(512 * j) * 4]
           + approx_gumbel(tf_pxor(gbase + (unsigned)(t + 512 * j)));
  } else {
    const unsigned short* sp = (const unsigned short*)scores_raw;
#pragma unroll
    for (int j = 0; j < 16; ++j)
      f[j] = __uint_as_float(((unsigned)sp[ebase0 + (size_t)(512 * j) * 4]) << 16)
           + approx_gumbel(tf_pxor(gbase + (unsigned)(t + 512 * j)));
  }

  // ---- block max (same value as before: max over same multiset) ----
  float m = f[0];
#pragma unroll
  for (int j = 1; j < 16; ++j) m = fmaxf(m, f[j]);
#pragma unroll
  for (int off = 32; off >= 1; off >>= 1) m = fmaxf(m, __shfl_xor(m, off));
  if (lane == 0) redM[wave] = m;
  __syncthreads();
#pragma unroll
  for (int w = 0; w < 8; ++w) m = fmaxf(m, redM[w]);

  // ---- bisect theta33: identical midpoint sequence (same m, same counts) ----
  float lo = m - 25.0f, hi = m;
#pragma unroll 1
  for (int itb = 0; itb < 12; ++itb) {
    const float mid = 0.5f * (lo + hi);
    int c = 0;
#pragma unroll
    for (int j = 0; j < 16; ++j) c += (f[j] > mid) ? 1 : 0;
#pragma unroll
    for (int off = 32; off >= 1; off >>= 1) c += __shfl_xor(c, off);
    if (lane == 0) wtot[itb][wave] = c;
    __syncthreads();
    int tot = 0;
#pragma unroll
    for (int w = 0; w < 8; ++w) tot += wtot[itb][w];
    if (tot >= 33) lo = mid; else hi = mid;
  }
  const float theta = lo - 2.34f;   // superset proof margin (r12-r18)

  // ---- compact (prefix order by (wave,lane,j)) + inline exact cf ----
  int cj = 0;
#pragma unroll
  for (int j = 0; j < 16; ++j) cj += (f[j] > theta) ? 1 : 0;
  int incv = cj;
#pragma unroll
  for (int off = 1; off < 64; off <<= 1) {
    const int v = __shfl_up(incv, off);
    if (lane >= off) incv += v;
  }
  if (lane == 63) wtot[12][wave] = incv;
  __syncthreads();
  int base = 0;
  for (int w = 0; w < wave; ++w) base += wtot[12][w];
  int cnt = 0;
#pragma unroll
  for (int w = 0; w < 8; ++w) cnt += wtot[12][w];
  if (cnt > CMAX) cnt = CMAX;
  if (t == 0) cntArr[r] = cnt;

  int o = base + incv - cj;
  if (cj > 0) {
    const size_t rowoff = (size_t)r * CMAX;
#pragma unroll 1
    for (int j = 0; j < 16; ++j) {
      if (f[j] > theta) {
        if (o < CMAX) {
          const int n = t + 512 * j;
          const size_t ei = ((size_t)b * ROWN + (size_t)n) * 4 + (size_t)e;
          float sc;
          if (in_f32) sc = ((const float*)scores_raw)[ei];
          else sc = __uint_as_float(((unsigned)((const unsigned short*)scores_raw)[ei]) << 16);
          idxArr[rowoff + o] = (unsigned short)n;
          cfArr[rowoff + o]  = sc + gumbel_of(gbase + (unsigned)n);   // bit-exact
        }
        ++o;
      }
    }
  }
}

// =====================================================================
// Kernel B: dynamics, ONE WAVE per row (grid 2048 x 64 thr). Own kernel
// so its latency tail doesn't hold phase-1 block slots (r3's mistake).
// Math bit-identical to r3's proven register path (absmax 0.0).
// =====================================================================
__global__ __launch_bounds__(64)
void dyn_row(const unsigned short* __restrict__ idxArr,
             const float* __restrict__ cfArr,
             const int* __restrict__ cntArr,
             int* __restrict__ selws) {
  const int lane = threadIdx.x;     // 0..63
  const int r    = blockIdx.x;      // 0..2047
  const int cnt  = cntArr[r];
  const size_t rowoff = (size_t)r * CMAX;

  __shared__ float cfL[CMAX];       // fallback path only (cnt>512, +9 sigma)
  __shared__ float khL[CMAX];
  __shared__ int   idL[CMAX];

  if (cnt <= 512) {
    // ---- 8-chunk register path ----
    float cfr[8], khr[8], ek[8];
    int   idxr[8];
#pragma unroll
    for (int p = 0; p < 8; ++p) {
      cfr[p] = -3.0e38f; khr[p] = -3.0e38f; idxr[p] = 0x7FFFFFFF;
      if (64 * p < cnt) {             // wave-uniform chunk skip
        const int ci = lane + 64 * p;
        if (ci < cnt) {
          cfr[p] = cfArr[rowoff + ci];
          khr[p] = 0.0f;
          idxr[p] = (int)idxArr[rowoff + ci];
        }
      }
    }

    // 32 np-faithful dynamics iterations, 12 shfl/iter, NO barriers
#pragma unroll 1
    for (int it = 0; it < 32; ++it) {
      float m2 = -3.4e38f;
#pragma unroll
      for (int p = 0; p < 8; ++p)
        if (64 * p < cnt) m2 = fmaxf(m2, cfr[p]);
#pragma unroll
      for (int off = 32; off >= 1; off >>= 1) m2 = fmaxf(m2, __shfl_xor(m2, off));
      const float xm = m2 / 0.1f;

      float Z = 0.0f;
#pragma unroll
      for (int p = 0; p < 8; ++p) {
        float ev = 0.0f;
        if (64 * p < cnt) {
          if (cfr[p] - m2 > -10.398f) { ev = expf(cfr[p] / 0.1f - xm); Z += ev; }
        }
        ek[p] = ev;
      }
#pragma unroll
      for (int off = 32; off >= 1; off >>= 1) Z += __shfl_xor(Z, off);

#pragma unroll
      for (int p = 0; p < 8; ++p) {
        if (64 * p < cnt && ek[p] > 0.0f) {
          const float pp = ek[p] / Z;
          khr[p] += pp;
          const float msk = 1.0f - pp;
          if (msk != 1.0f) cfr[p] += logf(fmaxf(msk, EPS_TINY));
        }
      }
    }

    // top-32 of khot, lowest-n tie-break, wave-local
#pragma unroll 1
    for (int pass = 0; pass < 32; ++pass) {
      float bv = -3.4e38f; int bi = 0x7FFFFFFF;
#pragma unroll
      for (int p = 0; p < 8; ++p) {
        if (64 * p < cnt) {
          const float v = khr[p]; const int ix = idxr[p];
          if (v > bv || (v == bv && ix < bi)) { bv = v; bi = ix; }
        }
      }
#pragma unroll
      for (int off = 32; off >= 1; off >>= 1) {
        const float ov = __shfl_xor(bv, off);
        const int   oi = __shfl_xor(bi, off);
        if (ov > bv || (ov == bv && oi < bi)) { bv = ov; bi = oi; }
      }
      if (lane == 0) selws[r * 32 + pass] = bi;
#pragma unroll
      for (int p = 0; p < 8; ++p)
        if (64 * p < cnt && idxr[p] == bi) khr[p] = -3.0e38f;
    }
  } else {
    // ---- LDS fallback for cnt in (512,1024] (never hit: +9 sigma) ----
    for (int ci = lane; ci < cnt; ci += 64) {
      cfL[ci] = cfArr[rowoff + ci];
      khL[ci] = 0.0f;
      idL[ci] = (int)idxArr[rowoff + ci];
    }
    __syncthreads();
    const int nch = (cnt + 63) >> 6;
#pragma unroll 1
    for (int it = 0; it < 32; ++it) {
      float m2 = -3.4e38f;
      for (int c = 0; c < nch; ++c) {
        const int ci = lane + 64 * c;
        if (ci < cnt) m2 = fmaxf(m2, cfL[ci]);
      }
#pragma unroll
      for (int off = 32; off >= 1; off >>= 1) m2 = fmaxf(m2, __shfl_xor(m2, off));
      const float xm = m2 / 0.1f;
      float Z = 0.0f;
      for (int c = 0; c < nch; ++c) {
        const int ci = lane + 64 * c;
        if (ci < cnt) {
          const float cf = cfL[ci];
          if (cf - m2 > -10.398f) Z += expf(cf / 0.1f - xm);
        }
      }
#pragma unroll
      for (int off = 32; off >= 1; off >>= 1) Z += __shfl_xor(Z, off);
      for (int c = 0; c < nch; ++c) {
        const int ci = lane + 64 * c;
        if (ci < cnt) {
          const float cf = cfL[ci];
          if (cf - m2 > -10.398f) {
            const float ev = expf(cf / 0.1f - xm);
            if (ev > 0.0f) {
              const float pp = ev / Z;
              khL[ci] += pp;
              const float msk = 1.0f - pp;
              if (msk != 1.0f) cfL[ci] = cf + logf(fmaxf(msk, EPS_TINY));
            }
          }
        }
      }
    }
#pragma unroll 1
    for (int pass = 0; pass < 32; ++pass) {
      float bv = -3.4e38f; int bi = 0x7FFFFFFF;
      for (int c = 0; c < nch; ++c) {
        const int ci = lane + 64 * c;
        if (ci < cnt) {
          const float v = khL[ci]; const int ix = idL[ci];
          if (v > bv || (v == bv && ix < bi)) { bv = v; bi = ix; }
        }
      }
#pragma unroll
      for (int off = 32; off >= 1; off >>= 1) {
        const float ov = __shfl_xor(bv, off);
        const int   oi = __shfl_xor(bi, off);
        if (ov > bv || (ov == bv && oi < bi)) { bv = ov; bi = oi; }
      }
      if (lane == 0) selws[r * 32 + pass] = bi;
      for (int c = 0; c < nch; ++c) {
        const int ci = lane + 64 * c;
        if (ci < cnt && idL[ci] == bi) khL[ci] = -3.0e38f;
      }
    }
  }
}

// =====================================================================
// Kernel C: bitmap expand -> coalesced float4 slab (unchanged, proven).
// =====================================================================
__global__ __launch_bounds__(TPB)
void expand_out(const int* __restrict__ selws, float4* __restrict__ out4) {
  const int t   = threadIdx.x;
  const int blk = blockIdx.x;        // 0..2047
  const int grp = blk >> 2;          // rep*256 + b
  const int s   = blk & 3;           // n-slice of 2048
  const int rep = grp >> 8;
  const int b   = grp & 255;

  __shared__ unsigned ebm[4 * 256];  // 4 e-planes x 8192 bits
#pragma unroll
  for (int p = 0; p < 4; ++p) ebm[t + 256 * p] = 0u;
  __syncthreads();
  if (t < 4) {
    const int r = rep * 1024 + b * 4 + t;
#pragma unroll 1
    for (int p = 0; p < 32; ++p) {
      const int ix = selws[r * 32 + p];
      ebm[t * 256 + (ix >> 5)] |= (1u << (ix & 31));
    }
  }
  __syncthreads();

  const size_t obase = (size_t)grp * ROWN;
#pragma unroll
  for (int j = 0; j < 8; ++j) {
    const int n = s * 2048 + t + 256 * j;
    float4 v;
    v.x = ((ebm[0 * 256 + (n >> 5)] >> (n & 31)) & 1u) ? 1.0f : 0.0f;
    v.y = ((ebm[1 * 256 + (n >> 5)] >> (n & 31)) & 1u) ? 1.0f : 0.0f;
    v.z = ((ebm[2 * 256 + (n >> 5)] >> (n & 31)) & 1u) ? 1.0f : 0.0f;
    v.w = ((ebm[3 * 256 + (n >> 5)] >> (n & 31)) & 1u) ? 1.0f : 0.0f;
    out4[obase + (size_t)n] = v;
  }
}

// =====================================================================
// Fallback fused kernel (round-1 verbatim, 197us proven, absmax 0.0) —
// used only if ws_size is too small for the split path's 12.8 MB.
// =====================================================================
__global__ __launch_bounds__(TPB, 8)
void topk_row_fused(const void* __restrict__ scores_raw, int* __restrict__ selws) {
  const int t    = threadIdx.x;
  const int lane = t & 63;
  const int wave = t >> 6;

  const int i   = blockIdx.x;
  const int xcd = i & 7;
  const int k   = i >> 3;
  const int e   = k & 3;
  const int q   = k >> 2;
  const int b   = xcd * 32 + (q & 31);
  const int rep = q >> 5;
  const int r   = rep * 1024 + b * 4 + e;
  const unsigned gbase = (unsigned)r * (unsigned)ROWN;

  __shared__ int   candIdx[CMAX];
  __shared__ float redM[4];
  __shared__ float redZ[4];
  __shared__ int   wtot[13][4];
  __shared__ float bV[2][4];
  __shared__ int   bI[2][4];
  __shared__ int   f32flag;

  if (t == 0) f32flag = 0;
  __syncthreads();
  {
    const unsigned* w = (const unsigned*)scores_raw;
    bool bad = false;
#pragma unroll
    for (int p = 0; p < 4; ++p) {
      const unsigned x = w[t + 256 * p];
      const float flo = __uint_as_float((x & 0xFFFFu) << 16);
      const float fhi = __uint_as_float(x & 0xFFFF0000u);
      if (!(fabsf(flo) <= 16.0f) || !(fabsf(fhi) <= 16.0f)) bad = true;
    }
    if (bad) f32flag = 1;
  }
  __syncthreads();
  const bool in_f32 = (f32flag != 0);

  const size_t ebase0 = ((size_t)b * ROWN + (size_t)t) * 4 + (size_t)e;
  float f[32];
  if (in_f32) {
    const float* sp = (const float*)scores_raw;
#pragma unroll
    for (int j = 0; j < 32; ++j)
      f[j] = sp[ebase0 + (size_t)(256 * j) * 4]
           + approx_gumbel(tf_pxor(gbase + (unsigned)(t + 256 * j)));
  } else {
    const unsigned short* sp = (const unsigned short*)scores_raw;
#pragma unroll
    for (int j = 0; j < 32; ++j)
      f[j] = __uint_as_float(((unsigned)sp[ebase0 + (size_t)(256 * j) * 4]) << 16)
           + approx_gumbel(tf_pxor(gbase + (unsigned)(t + 256 * j)));
  }

  float m = f[0];
#pragma unroll
  for (int j = 1; j < 32; ++j) m = fmaxf(m, f[j]);
#pragma unroll
  for (int off = 32; off >= 1; off >>= 1) m = fmaxf(m, __shfl_xor(m, off));
  if (lane == 0) redM[wave] = m;
  __syncthreads();
  m = fmaxf(fmaxf(redM[0], redM[1]), fmaxf(redM[2], redM[3]));

  float lo = m - 25.0f, hi = m;
#pragma unroll 1
  for (int itb = 0; itb < 12; ++itb) {
    const float mid = 0.5f * (lo + hi);
    int c = 0;
#pragma unroll
    for (int j = 0; j < 32; ++j) c += (f[j] > mid) ? 1 : 0;
#pragma unroll
    for (int off = 32; off >= 1; off >>= 1) c += __shfl_xor(c, off);
    if (lane == 0) wtot[itb][wave] = c;
    __syncthreads();
    const int tot = wtot[itb][0] + wtot[itb][1] + wtot[itb][2] + wtot[itb][3];
    if (tot >= 33) lo = mid; else hi = mid;
  }
  const float theta = lo - 2.34f;

  int cj = 0;
#pragma unroll
  for (int j = 0; j < 32; ++j) cj += (f[j] > theta) ? 1 : 0;
  int incv = cj;
#pragma unroll
  for (int off = 1; off < 64; off <<= 1) {
    const int v = __shfl_up(incv, off);
    if (lane >= off) incv += v;
  }
  if (lane == 63) wtot[12][wave] = incv;
  __syncthreads();
  int base = 0;
  for (int w = 0; w < wave; ++w) base += wtot[12][w];
  int cnt = wtot[12][0] + wtot[12][1] + wtot[12][2] + wtot[12][3];
  if (cnt > CMAX) cnt = CMAX;
  int o = base + incv - cj;
#pragma unroll
  for (int j = 0; j < 32; ++j) {
    if (f[j] > theta) {
      if (o < CMAX) candIdx[o] = t + 256 * j;
      ++o;
    }
  }
  __syncthreads();

  float cfr[4], khr[4];
  int   idxr[4];
#pragma unroll
  for (int p = 0; p < 4; ++p) {
    cfr[p] = -3.0e38f; khr[p] = -3.0e38f; idxr[p] = 0x7FFFFFFF;
    if (256 * p < cnt) {
      const int ci = t + 256 * p;
      if (ci < cnt) {
        const int n = candIdx[ci];
        const size_t ei = ((size_t)b * ROWN + (size_t)n) * 4 + (size_t)e;
        float sc;
        if (in_f32) sc = ((const float*)scores_raw)[ei];
        else sc = __uint_as_float(((unsigned)((const unsigned short*)scores_raw)[ei]) << 16);
        cfr[p] = sc + gumbel_of(gbase + (unsigned)n);
        khr[p] = 0.0f;
        idxr[p] = n;
      }
    }
  }

#pragma unroll 1
  for (int it = 0; it < 32; ++it) {
    float m2 = -3.4e38f;
#pragma unroll
    for (int p = 0; p < 4; ++p)
      if (256 * p < cnt) m2 = fmaxf(m2, cfr[p]);
#pragma unroll
    for (int off = 32; off >= 1; off >>= 1) m2 = fmaxf(m2, __shfl_xor(m2, off));
    if (lane == 0) redM[wave] = m2;
    __syncthreads();
    m2 = fmaxf(fmaxf(redM[0], redM[1]), fmaxf(redM[2], redM[3]));
    const float xm = m2 / 0.1f;

    float ek[4];
    float Z = 0.0f;
#pragma unroll
    for (int p = 0; p < 4; ++p) {
      float ev = 0.0f;
      if (256 * p < cnt) {
        if (cfr[p] - m2 > -10.398f) { ev = expf(cfr[p] / 0.1f - xm); Z += ev; }
      }
      ek[p] = ev;
    }
#pragma unroll
    for (int off = 32; off >= 1; off >>= 1) Z += __shfl_xor(Z, off);
    if (lane == 0) redZ[wave] = Z;
    __syncthreads();
    Z = (redZ[0] + redZ[1]) + (redZ[2] + redZ[3]);

#pragma unroll
    for (int p = 0; p < 4; ++p) {
      if (256 * p < cnt && ek[p] > 0.0f) {
        const float pp = ek[p] / Z;
        khr[p] += pp;
        const float msk = 1.0f - pp;
        if (msk != 1.0f) cfr[p] += logf(fmaxf(msk, EPS_TINY));
      }
    }
  }

#pragma unroll 1
  for (int pass = 0; pass < 32; ++pass) {
    float bv = -3.4e38f; int bi = 0x7FFFFFFF;
#pragma unroll
    for (int p = 0; p < 4; ++p) {
      if (256 * p < cnt) {
        const float v = khr[p]; const int ix = idxr[p];
        if (v > bv || (v == bv && ix < bi)) { bv = v; bi = ix; }
      }
    }
#pragma unroll
    for (int off = 32; off >= 1; off >>= 1) {
      const float ov = __shfl_xor(bv, off);
      const int   oi = __shfl_xor(bi, off);
      if (ov > bv || (ov == bv && oi < bi)) { bv = ov; bi = oi; }
    }
    if (lane == 0) { bV[pass & 1][wave] = bv; bI[pass & 1][wave] = bi; }
    __syncthreads();
#pragma unroll
    for (int w = 0; w < 4; ++w) {
      const float ov = bV[pass & 1][w]; const int oi = bI[pass & 1][w];
      if (ov > bv || (ov == bv && oi < bi)) { bv = ov; bi = oi; }
    }
    if (t == 0) selws[r * 32 + pass] = bi;
#pragma unroll
    for (int p = 0; p < 4; ++p)
      if (256 * p < cnt && idxr[p] == bi) khr[p] = -3.0e38f;
  }
}

extern "C" void kernel_launch(void* const* d_in, const int* in_sizes, int n_in,
                              void* d_out, int out_size, void* d_ws, size_t ws_size,
                              hipStream_t stream) {
  const void* scores = d_in[0];      // dtype autodetected in-kernel
  const size_t IDX_BYTES = 2048ull * CMAX * 2;   //  4 MB u16 idx
  const size_t CF_BYTES  = 2048ull * CMAX * 4;   //  8 MB f32 cf
  const size_t CNT_BYTES = 2048ull * 4;          //  8 KB
  const size_t SEL_BYTES = 2048ull * 32 * 4;     // 256 KB
  const size_t need = IDX_BYTES + CF_BYTES + CNT_BYTES + SEL_BYTES;

  if (ws_size >= need) {
    unsigned short* idxArr = (unsigned short*)d_ws;
    float* cfArr = (float*)((char*)d_ws + IDX_BYTES);
    int*   cntArr = (int*)((char*)d_ws + IDX_BYTES + CF_BYTES);
    int*   selws  = (int*)((char*)d_ws + IDX_BYTES + CF_BYTES + CNT_BYTES);
    gen_compact<<<dim3(2048), dim3(512), 0, stream>>>(scores, idxArr, cfArr, cntArr);
    dyn_row<<<dim3(2048), dim3(64), 0, stream>>>(idxArr, cfArr, cntArr, selws);
    expand_out<<<dim3(2048), dim3(TPB), 0, stream>>>(selws, (float4*)d_out);
  } else {
    int* selws = (int*)d_ws;         // 256 KB (round-1 proven path)
    topk_row_fused<<<dim3(2048), dim3(TPB), 0, stream>>>(scores, selws);
    expand_out<<<dim3(2048), dim3(TPB), 0, stream>>>(selws, (float4*)d_out);
  }
}

// Round 5
// 271.102 us; speedup vs baseline: 1.5221x; 1.5221x over previous
//
#include <hip/hip_runtime.h>

#define TPB 256
#define ROWN 8192
#define CMAX 1024   // per-row candidate cap (r12-r18 proven never hit)
#define EPS_TINY 1.1754943508222875e-38f   // np.finfo(np.float32).tiny

__device__ __forceinline__ unsigned rotl32(unsigned x, int r) {
  return (x << r) | (x >> (32 - r));
}

// threefry2x32, key (0,42), partitionable counters: ctr=(0,idx), bits = x0^x1.
// Verified on-device (r11 decode; r12-r18 absmax 0.0).
__device__ __forceinline__ unsigned tf_pxor(unsigned idx) {
  const unsigned ks0 = 0u, ks1 = 42u, ks2 = 0x1BD11BDAu ^ 0u ^ 42u;
  unsigned x0 = ks0;
  unsigned x1 = idx + ks1;
#define TF4(a,b,cc,d) \
  x0 += x1; x1 = rotl32(x1,(a));  x1 ^= x0; \
  x0 += x1; x1 = rotl32(x1,(b));  x1 ^= x0; \
  x0 += x1; x1 = rotl32(x1,(cc)); x1 ^= x0; \
  x0 += x1; x1 = rotl32(x1,(d));  x1 ^= x0;
  TF4(13,15,26,6)   x0 += ks1; x1 += ks2 + 1u;
  TF4(17,29,16,24)  x0 += ks2; x1 += ks0 + 2u;
  TF4(13,15,26,6)   x0 += ks0; x1 += ks1 + 3u;
  TF4(17,29,16,24)  x0 += ks1; x1 += ks2 + 4u;
  TF4(13,15,26,6)   x0 += ks2; x1 += ks0 + 5u;
#undef TF4
  return x0 ^ x1;
}

// EXACT jax gumbel (precise ocml logf) — candidates only, bit-exact.
__device__ __forceinline__ float gumbel_of(unsigned idx) {
  const unsigned bits = tf_pxor(idx);
  float u = __uint_as_float((bits >> 9) | 0x3f800000u) - 1.0f;
  u = u + EPS_TINY;
  u = fmaxf(EPS_TINY, u);
  return -logf(-logf(u));
}

// APPROX gumbel for the filter pass: |err| <= ~2e-4 (proven r15-r18).
__device__ __forceinline__ float approx_gumbel(unsigned bits) {
  float u = __uint_as_float((bits >> 9) | 0x3f800000u) - 1.0f;
  u = u + EPS_TINY;
  u = fmaxf(EPS_TINY, u);
  float t;
  if (u >= 0.75f) {
    const float v = 1.0f - u;   // exact (Sterbenz)
    t = v * (1.0f + v * (0.5f + v * (0.33333334f + v * (0.25f + v * 0.2f))));
  } else {
    t = -0.69314718f * __log2f(u);
  }
  return -0.69314718f * __log2f(t);
}

// =====================================================================
// Fused kernel: one block per (rep, b, e) ROW. grid=2048, 256 thr.
// IDENTICAL to the round-1 197us/absmax-0.0 kernel except
// __launch_bounds__(256, 4): r1's (256,8) capped VGPRs at 64, spilling
// f[32] to scratch (VGPR_Count=32, WRITE_SIZE=39MB of scratch traffic,
// 384 scratch re-reads/thread in the bisect). (256,4) = 128-VGPR budget
// -> f[32] stays in registers; 4 blocks/CU (16 waves/CU) — same HW
// occupancy tier (VGPR 64..128 => 4 waves/SIMD), zero spill.
// gen (issue-bound) and dynamics (latency-bound) phases of co-resident
// blocks overlap — r4 proved the split loses 1.8x to serialization.
// =====================================================================
__global__ __launch_bounds__(TPB, 4)
void topk_row(const void* __restrict__ scores_raw, int* __restrict__ selws) {
  const int t    = threadIdx.x;
  const int lane = t & 63;
  const int wave = t >> 6;

  // XCD grouping: all 8 rows (4e x 2rep) of input panel b land on one XCD.
  const int i   = blockIdx.x;       // 0..2047
  const int xcd = i & 7;
  const int k   = i >> 3;           // 0..255
  const int e   = k & 3;
  const int q   = k >> 2;           // 0..63
  const int b   = xcd * 32 + (q & 31);
  const int rep = q >> 5;
  const int r   = rep * 1024 + b * 4 + e;
  const unsigned gbase = (unsigned)r * (unsigned)ROWN;

  __shared__ int   candIdx[CMAX];     // 4 KB
  __shared__ float redM[4];
  __shared__ float redZ[4];
  __shared__ int   wtot[13][4];
  __shared__ float bV[2][4];
  __shared__ int   bI[2][4];
  __shared__ int   f32flag;

  // ---- input dtype autodetect (4 KB prefix; proven r11-r18) ----
  if (t == 0) f32flag = 0;
  __syncthreads();
  {
    const unsigned* w = (const unsigned*)scores_raw;
    bool bad = false;
#pragma unroll
    for (int p = 0; p < 4; ++p) {
      const unsigned x = w[t + 256 * p];
      const float flo = __uint_as_float((x & 0xFFFFu) << 16);
      const float fhi = __uint_as_float(x & 0xFFFF0000u);
      if (!(fabsf(flo) <= 16.0f) || !(fabsf(fhi) <= 16.0f)) bad = true;
    }
    if (bad) f32flag = 1;
  }
  __syncthreads();
  const bool in_f32 = (f32flag != 0);

  // ================= phase 1: gen -> theta -> compact (single row) ======
  const size_t ebase0 = ((size_t)b * ROWN + (size_t)t) * 4 + (size_t)e;
  float f[32];
  if (in_f32) {
    const float* sp = (const float*)scores_raw;
#pragma unroll
    for (int j = 0; j < 32; ++j)
      f[j] = sp[ebase0 + (size_t)(256 * j) * 4]
           + approx_gumbel(tf_pxor(gbase + (unsigned)(t + 256 * j)));
  } else {
    const unsigned short* sp = (const unsigned short*)scores_raw;
#pragma unroll
    for (int j = 0; j < 32; ++j)
      f[j] = __uint_as_float(((unsigned)sp[ebase0 + (size_t)(256 * j) * 4]) << 16)
           + approx_gumbel(tf_pxor(gbase + (unsigned)(t + 256 * j)));
  }

  // block max
  float m = f[0];
#pragma unroll
  for (int j = 1; j < 32; ++j) m = fmaxf(m, f[j]);
#pragma unroll
  for (int off = 32; off >= 1; off >>= 1) m = fmaxf(m, __shfl_xor(m, off));
  if (lane == 0) redM[wave] = m;
  __syncthreads();
  m = fmaxf(fmaxf(redM[0], redM[1]), fmaxf(redM[2], redM[3]));

  // bisect theta33 (12 iters, resolution 25/4096 ~ 6e-3)
  float lo = m - 25.0f, hi = m;
#pragma unroll 1
  for (int itb = 0; itb < 12; ++itb) {
    const float mid = 0.5f * (lo + hi);
    int c = 0;
#pragma unroll
    for (int j = 0; j < 32; ++j) c += (f[j] > mid) ? 1 : 0;
#pragma unroll
    for (int off = 32; off >= 1; off >>= 1) c += __shfl_xor(c, off);
    if (lane == 0) wtot[itb][wave] = c;
    __syncthreads();
    const int tot = wtot[itb][0] + wtot[itb][1] + wtot[itb][2] + wtot[itb][3];
    if (tot >= 33) lo = mid; else hi = mid;
  }
  const float theta = lo - 2.34f;   // superset proof margin (r12-r18)

  // compact candidate indices (deterministic prefix order)
  int cj = 0;
#pragma unroll
  for (int j = 0; j < 32; ++j) cj += (f[j] > theta) ? 1 : 0;
  int incv = cj;
#pragma unroll
  for (int off = 1; off < 64; off <<= 1) {
    const int v = __shfl_up(incv, off);
    if (lane >= off) incv += v;
  }
  if (lane == 63) wtot[12][wave] = incv;
  __syncthreads();
  int base = 0;
  for (int w = 0; w < wave; ++w) base += wtot[12][w];
  int cnt = wtot[12][0] + wtot[12][1] + wtot[12][2] + wtot[12][3];
  if (cnt > CMAX) cnt = CMAX;
  int o = base + incv - cj;
#pragma unroll
  for (int j = 0; j < 32; ++j) {
    if (f[j] > theta) {
      if (o < CMAX) candIdx[o] = t + 256 * j;
      ++o;
    }
  }
  __syncthreads();   // candIdx visible to whole block

  // ================= phase 2: block-wide dynamics (4 chunks of 256) =====
  float cfr[4], khr[4];
  int   idxr[4];
#pragma unroll
  for (int p = 0; p < 4; ++p) {
    cfr[p] = -3.0e38f; khr[p] = -3.0e38f; idxr[p] = 0x7FFFFFFF;
    if (256 * p < cnt) {               // block-uniform chunk skip
      const int ci = t + 256 * p;
      if (ci < cnt) {
        const int n = candIdx[ci];
        const size_t ei = ((size_t)b * ROWN + (size_t)n) * 4 + (size_t)e;
        float sc;
        if (in_f32) sc = ((const float*)scores_raw)[ei];
        else sc = __uint_as_float(((unsigned)((const unsigned short*)scores_raw)[ei]) << 16);
        cfr[p] = sc + gumbel_of(gbase + (unsigned)n);   // bit-exact
        khr[p] = 0.0f;
        idxr[p] = n;
      }
    }
  }

  // 32 np-faithful dynamics iterations; 2 barriers/iter, distinct LDS arrays
  // (write redM / barA / read redM / write redZ / barB / read redZ -> safe).
#pragma unroll 1
  for (int it = 0; it < 32; ++it) {
    float m2 = -3.4e38f;
#pragma unroll
    for (int p = 0; p < 4; ++p)
      if (256 * p < cnt) m2 = fmaxf(m2, cfr[p]);
#pragma unroll
    for (int off = 32; off >= 1; off >>= 1) m2 = fmaxf(m2, __shfl_xor(m2, off));
    if (lane == 0) redM[wave] = m2;
    __syncthreads();
    m2 = fmaxf(fmaxf(redM[0], redM[1]), fmaxf(redM[2], redM[3]));
    const float xm = m2 / 0.1f;

    float ek[4];
    float Z = 0.0f;
#pragma unroll
    for (int p = 0; p < 4; ++p) {
      float ev = 0.0f;
      if (256 * p < cnt) {
        if (cfr[p] - m2 > -10.398f) { ev = expf(cfr[p] / 0.1f - xm); Z += ev; }
      }
      ek[p] = ev;
    }
#pragma unroll
    for (int off = 32; off >= 1; off >>= 1) Z += __shfl_xor(Z, off);
    if (lane == 0) redZ[wave] = Z;
    __syncthreads();
    Z = (redZ[0] + redZ[1]) + (redZ[2] + redZ[3]);   // fixed deterministic order

#pragma unroll
    for (int p = 0; p < 4; ++p) {
      if (256 * p < cnt && ek[p] > 0.0f) {
        const float pp = ek[p] / Z;
        khr[p] += pp;
        const float msk = 1.0f - pp;
        if (msk != 1.0f) cfr[p] += logf(fmaxf(msk, EPS_TINY));
      }
    }
  }

  // top-32 of khot, lowest-n tie-break, block-wide (double-buffered slots)
#pragma unroll 1
  for (int pass = 0; pass < 32; ++pass) {
    float bv = -3.4e38f; int bi = 0x7FFFFFFF;
#pragma unroll
    for (int p = 0; p < 4; ++p) {
      if (256 * p < cnt) {
        const float v = khr[p]; const int ix = idxr[p];
        if (v > bv || (v == bv && ix < bi)) { bv = v; bi = ix; }
      }
    }
#pragma unroll
    for (int off = 32; off >= 1; off >>= 1) {
      const float ov = __shfl_xor(bv, off);
      const int   oi = __shfl_xor(bi, off);
      if (ov > bv || (ov == bv && oi < bi)) { bv = ov; bi = oi; }
    }
    if (lane == 0) { bV[pass & 1][wave] = bv; bI[pass & 1][wave] = bi; }
    __syncthreads();
#pragma unroll
    for (int w = 0; w < 4; ++w) {
      const float ov = bV[pass & 1][w]; const int oi = bI[pass & 1][w];
      if (ov > bv || (ov == bv && oi < bi)) { bv = ov; bi = oi; }
    }
    if (t == 0) selws[r * 32 + pass] = bi;
#pragma unroll
    for (int p = 0; p < 4; ++p)
      if (256 * p < cnt && idxr[p] == bi) khr[p] = -3.0e38f;
  }
}

// =====================================================================
// Kernel 2: bitmap expand -> coalesced float4 slab (unchanged, proven).
// =====================================================================
__global__ __launch_bounds__(TPB)
void expand_out(const int* __restrict__ selws, float4* __restrict__ out4) {
  const int t   = threadIdx.x;
  const int blk = blockIdx.x;        // 0..2047
  const int grp = blk >> 2;          // rep*256 + b
  const int s   = blk & 3;           // n-slice of 2048
  const int rep = grp >> 8;
  const int b   = grp & 255;

  __shared__ unsigned ebm[4 * 256];  // 4 e-planes x 8192 bits
#pragma unroll
  for (int p = 0; p < 4; ++p) ebm[t + 256 * p] = 0u;
  __syncthreads();
  if (t < 4) {
    const int r = rep * 1024 + b * 4 + t;
#pragma unroll 1
    for (int p = 0; p < 32; ++p) {
      const int ix = selws[r * 32 + p];
      ebm[t * 256 + (ix >> 5)] |= (1u << (ix & 31));
    }
  }
  __syncthreads();

  const size_t obase = (size_t)grp * ROWN;
#pragma unroll
  for (int j = 0; j < 8; ++j) {
    const int n = s * 2048 + t + 256 * j;
    float4 v;
    v.x = ((ebm[0 * 256 + (n >> 5)] >> (n & 31)) & 1u) ? 1.0f : 0.0f;
    v.y = ((ebm[1 * 256 + (n >> 5)] >> (n & 31)) & 1u) ? 1.0f : 0.0f;
    v.z = ((ebm[2 * 256 + (n >> 5)] >> (n & 31)) & 1u) ? 1.0f : 0.0f;
    v.w = ((ebm[3 * 256 + (n >> 5)] >> (n & 31)) & 1u) ? 1.0f : 0.0f;
    out4[obase + (size_t)n] = v;
  }
}

extern "C" void kernel_launch(void* const* d_in, const int* in_sizes, int n_in,
                              void* d_out, int out_size, void* d_ws, size_t ws_size,
                              hipStream_t stream) {
  const void* scores = d_in[0];      // dtype autodetected in-kernel
  int* selws = (int*)d_ws;           // 2048 rows x 32 ints = 256 KB
  topk_row<<<dim3(2048), dim3(TPB), 0, stream>>>(scores, selws);
  expand_out<<<dim3(2048), dim3(TPB), 0, stream>>>(selws, (float4*)d_out);
}

// Round 6
// 253.468 us; speedup vs baseline: 1.6280x; 1.0696x over previous
//
#include <hip/hip_runtime.h>

#define TPB 256
#define ROWN 8192
#define CMAX 1024   // per-row candidate cap (r12-r18 proven never hit)
#define EPS_TINY 1.1754943508222875e-38f   // np.finfo(np.float32).tiny

__device__ __forceinline__ unsigned rotl32(unsigned x, int r) {
  return (x << r) | (x >> (32 - r));
}

// threefry2x32, key (0,42), partitionable counters: ctr=(0,idx), bits = x0^x1.
// Verified on-device (r11 decode; r12-r18 absmax 0.0).
__device__ __forceinline__ unsigned tf_pxor(unsigned idx) {
  const unsigned ks0 = 0u, ks1 = 42u, ks2 = 0x1BD11BDAu ^ 0u ^ 42u;
  unsigned x0 = ks0;
  unsigned x1 = idx + ks1;
#define TF4(a,b,cc,d) \
  x0 += x1; x1 = rotl32(x1,(a));  x1 ^= x0; \
  x0 += x1; x1 = rotl32(x1,(b));  x1 ^= x0; \
  x0 += x1; x1 = rotl32(x1,(cc)); x1 ^= x0; \
  x0 += x1; x1 = rotl32(x1,(d));  x1 ^= x0;
  TF4(13,15,26,6)   x0 += ks1; x1 += ks2 + 1u;
  TF4(17,29,16,24)  x0 += ks2; x1 += ks0 + 2u;
  TF4(13,15,26,6)   x0 += ks0; x1 += ks1 + 3u;
  TF4(17,29,16,24)  x0 += ks1; x1 += ks2 + 4u;
  TF4(13,15,26,6)   x0 += ks2; x1 += ks0 + 5u;
#undef TF4
  return x0 ^ x1;
}

// EXACT jax gumbel (precise ocml logf) — candidates only, bit-exact.
__device__ __forceinline__ float gumbel_of(unsigned idx) {
  const unsigned bits = tf_pxor(idx);
  float u = __uint_as_float((bits >> 9) | 0x3f800000u) - 1.0f;
  u = u + EPS_TINY;
  u = fmaxf(EPS_TINY, u);
  return -logf(-logf(u));
}

// APPROX gumbel for the filter pass: |err| <= ~2e-4 (proven r15-r18).
__device__ __forceinline__ float approx_gumbel(unsigned bits) {
  float u = __uint_as_float((bits >> 9) | 0x3f800000u) - 1.0f;
  u = u + EPS_TINY;
  u = fmaxf(EPS_TINY, u);
  float t;
  if (u >= 0.75f) {
    const float v = 1.0f - u;   // exact (Sterbenz)
    t = v * (1.0f + v * (0.5f + v * (0.33333334f + v * (0.25f + v * 0.2f))));
  } else {
    t = -0.69314718f * __log2f(u);
  }
  return -0.69314718f * __log2f(t);
}

// =====================================================================
// Fused kernel: one block per (rep, b, e) ROW. grid=2048, 256 thr.
// r5 structure (256,4: f[32] lives in AGPRs, zero scratch — proven
// absmax 0.0 / 239us) + ONE change: dynamics fast-math diet.
//   - ocml expf (~30 insts) -> __expf((cf-m2)*10)  [1 mul + v_exp]
//   - 5 IEEE divs/iter (~75 insts) -> 1 v_rcp + multiplies
//   - ocml logf -> __logf
//   - branchless: exp(-inf)=0 and __logf(1.0f)=0 make inactive lanes
//     bitwise no-ops; Z is bit-identical (subnormal adds vanish vs Z>=1).
// Output is a 0/1 mask; kept/dropped khot gaps are O(1), so 1e-7-rel
// perturbation cannot flip the selected set. Exact gumbel_of cf kept.
// =====================================================================
__global__ __launch_bounds__(TPB, 4)
void topk_row(const void* __restrict__ scores_raw, int* __restrict__ selws) {
  const int t    = threadIdx.x;
  const int lane = t & 63;
  const int wave = t >> 6;

  // XCD grouping: all 8 rows (4e x 2rep) of input panel b land on one XCD.
  const int i   = blockIdx.x;       // 0..2047
  const int xcd = i & 7;
  const int k   = i >> 3;           // 0..255
  const int e   = k & 3;
  const int q   = k >> 2;           // 0..63
  const int b   = xcd * 32 + (q & 31);
  const int rep = q >> 5;
  const int r   = rep * 1024 + b * 4 + e;
  const unsigned gbase = (unsigned)r * (unsigned)ROWN;

  __shared__ int   candIdx[CMAX];     // 4 KB
  __shared__ float redM[4];
  __shared__ float redZ[4];
  __shared__ int   wtot[13][4];
  __shared__ float bV[2][4];
  __shared__ int   bI[2][4];
  __shared__ int   f32flag;

  // ---- input dtype autodetect (4 KB prefix; proven r11-r18) ----
  if (t == 0) f32flag = 0;
  __syncthreads();
  {
    const unsigned* w = (const unsigned*)scores_raw;
    bool bad = false;
#pragma unroll
    for (int p = 0; p < 4; ++p) {
      const unsigned x = w[t + 256 * p];
      const float flo = __uint_as_float((x & 0xFFFFu) << 16);
      const float fhi = __uint_as_float(x & 0xFFFF0000u);
      if (!(fabsf(flo) <= 16.0f) || !(fabsf(fhi) <= 16.0f)) bad = true;
    }
    if (bad) f32flag = 1;
  }
  __syncthreads();
  const bool in_f32 = (f32flag != 0);

  // ================= phase 1: gen -> theta -> compact (single row) ======
  const size_t ebase0 = ((size_t)b * ROWN + (size_t)t) * 4 + (size_t)e;
  float f[32];
  if (in_f32) {
    const float* sp = (const float*)scores_raw;
#pragma unroll
    for (int j = 0; j < 32; ++j)
      f[j] = sp[ebase0 + (size_t)(256 * j) * 4]
           + approx_gumbel(tf_pxor(gbase + (unsigned)(t + 256 * j)));
  } else {
    const unsigned short* sp = (const unsigned short*)scores_raw;
#pragma unroll
    for (int j = 0; j < 32; ++j)
      f[j] = __uint_as_float(((unsigned)sp[ebase0 + (size_t)(256 * j) * 4]) << 16)
           + approx_gumbel(tf_pxor(gbase + (unsigned)(t + 256 * j)));
  }

  // block max
  float m = f[0];
#pragma unroll
  for (int j = 1; j < 32; ++j) m = fmaxf(m, f[j]);
#pragma unroll
  for (int off = 32; off >= 1; off >>= 1) m = fmaxf(m, __shfl_xor(m, off));
  if (lane == 0) redM[wave] = m;
  __syncthreads();
  m = fmaxf(fmaxf(redM[0], redM[1]), fmaxf(redM[2], redM[3]));

  // bisect theta33 (12 iters, resolution 25/4096 ~ 6e-3)
  float lo = m - 25.0f, hi = m;
#pragma unroll 1
  for (int itb = 0; itb < 12; ++itb) {
    const float mid = 0.5f * (lo + hi);
    int c = 0;
#pragma unroll
    for (int j = 0; j < 32; ++j) c += (f[j] > mid) ? 1 : 0;
#pragma unroll
    for (int off = 32; off >= 1; off >>= 1) c += __shfl_xor(c, off);
    if (lane == 0) wtot[itb][wave] = c;
    __syncthreads();
    const int tot = wtot[itb][0] + wtot[itb][1] + wtot[itb][2] + wtot[itb][3];
    if (tot >= 33) lo = mid; else hi = mid;
  }
  const float theta = lo - 2.34f;   // superset proof margin (r12-r18)

  // compact candidate indices (deterministic prefix order)
  int cj = 0;
#pragma unroll
  for (int j = 0; j < 32; ++j) cj += (f[j] > theta) ? 1 : 0;
  int incv = cj;
#pragma unroll
  for (int off = 1; off < 64; off <<= 1) {
    const int v = __shfl_up(incv, off);
    if (lane >= off) incv += v;
  }
  if (lane == 63) wtot[12][wave] = incv;
  __syncthreads();
  int base = 0;
  for (int w = 0; w < wave; ++w) base += wtot[12][w];
  int cnt = wtot[12][0] + wtot[12][1] + wtot[12][2] + wtot[12][3];
  if (cnt > CMAX) cnt = CMAX;
  int o = base + incv - cj;
#pragma unroll
  for (int j = 0; j < 32; ++j) {
    if (f[j] > theta) {
      if (o < CMAX) candIdx[o] = t + 256 * j;
      ++o;
    }
  }
  __syncthreads();   // candIdx visible to whole block

  // ================= phase 2: block-wide dynamics (4 chunks of 256) =====
  float cfr[4], khr[4];
  int   idxr[4];
#pragma unroll
  for (int p = 0; p < 4; ++p) {
    cfr[p] = -3.0e38f; khr[p] = -3.0e38f; idxr[p] = 0x7FFFFFFF;
    if (256 * p < cnt) {               // block-uniform chunk skip
      const int ci = t + 256 * p;
      if (ci < cnt) {
        const int n = candIdx[ci];
        const size_t ei = ((size_t)b * ROWN + (size_t)n) * 4 + (size_t)e;
        float sc;
        if (in_f32) sc = ((const float*)scores_raw)[ei];
        else sc = __uint_as_float(((unsigned)((const unsigned short*)scores_raw)[ei]) << 16);
        cfr[p] = sc + gumbel_of(gbase + (unsigned)n);   // bit-exact
        khr[p] = 0.0f;
        idxr[p] = n;
      }
    }
  }

  // 32 dynamics iterations; 2 barriers/iter, distinct LDS arrays (safe).
  // Fast-math inner ops (see header comment): branchless per-chunk body.
#pragma unroll 1
  for (int it = 0; it < 32; ++it) {
    float m2 = -3.4e38f;
#pragma unroll
    for (int p = 0; p < 4; ++p)
      if (256 * p < cnt) m2 = fmaxf(m2, cfr[p]);
#pragma unroll
    for (int off = 32; off >= 1; off >>= 1) m2 = fmaxf(m2, __shfl_xor(m2, off));
    if (lane == 0) redM[wave] = m2;
    __syncthreads();
    m2 = fmaxf(fmaxf(redM[0], redM[1]), fmaxf(redM[2], redM[3]));

    float ek[4];
    float Z = 0.0f;
#pragma unroll
    for (int p = 0; p < 4; ++p) {
      float ev = 0.0f;
      if (256 * p < cnt) {
        // filler cfr=-3e38: (cfr-m2)*10 -> -inf -> ev = 0 (exact no-op)
        ev = __expf((cfr[p] - m2) * 10.0f);
        Z += ev;
      }
      ek[p] = ev;
    }
#pragma unroll
    for (int off = 32; off >= 1; off >>= 1) Z += __shfl_xor(Z, off);
    if (lane == 0) redZ[wave] = Z;
    __syncthreads();
    Z = (redZ[0] + redZ[1]) + (redZ[2] + redZ[3]);   // fixed deterministic order

    const float rz = __builtin_amdgcn_rcpf(Z);       // Z in [1, cnt]; rel err ~1e-7
#pragma unroll
    for (int p = 0; p < 4; ++p) {
      if (256 * p < cnt) {
        const float pp = ek[p] * rz;                 // 0 for inactive lanes
        khr[p] += pp;                                // += 0 is bitwise no-op
        // pp<2^-25 -> 1-pp==1.0 -> __logf(1)=0 -> bitwise no-op;
        // pp~1 -> fmaxf guards 1-pp<=0 against -inf/NaN.
        cfr[p] += __logf(fmaxf(1.0f - pp, EPS_TINY));
      }
    }
  }

  // top-32 of khot, lowest-n tie-break, block-wide (double-buffered slots)
#pragma unroll 1
  for (int pass = 0; pass < 32; ++pass) {
    float bv = -3.4e38f; int bi = 0x7FFFFFFF;
#pragma unroll
    for (int p = 0; p < 4; ++p) {
      if (256 * p < cnt) {
        const float v = khr[p]; const int ix = idxr[p];
        if (v > bv || (v == bv && ix < bi)) { bv = v; bi = ix; }
      }
    }
#pragma unroll
    for (int off = 32; off >= 1; off >>= 1) {
      const float ov = __shfl_xor(bv, off);
      const int   oi = __shfl_xor(bi, off);
      if (ov > bv || (ov == bv && oi < bi)) { bv = ov; bi = oi; }
    }
    if (lane == 0) { bV[pass & 1][wave] = bv; bI[pass & 1][wave] = bi; }
    __syncthreads();
#pragma unroll
    for (int w = 0; w < 4; ++w) {
      const float ov = bV[pass & 1][w]; const int oi = bI[pass & 1][w];
      if (ov > bv || (ov == bv && oi < bi)) { bv = ov; bi = oi; }
    }
    if (t == 0) selws[r * 32 + pass] = bi;
#pragma unroll
    for (int p = 0; p < 4; ++p)
      if (256 * p < cnt && idxr[p] == bi) khr[p] = -3.0e38f;
  }
}

// =====================================================================
// Kernel 2: bitmap expand -> coalesced float4 slab (unchanged, proven).
// =====================================================================
__global__ __launch_bounds__(TPB)
void expand_out(const int* __restrict__ selws, float4* __restrict__ out4) {
  const int t   = threadIdx.x;
  const int blk = blockIdx.x;        // 0..2047
  const int grp = blk >> 2;          // rep*256 + b
  const int s   = blk & 3;           // n-slice of 2048
  const int rep = grp >> 8;
  const int b   = grp & 255;

  __shared__ unsigned ebm[4 * 256];  // 4 e-planes x 8192 bits
#pragma unroll
  for (int p = 0; p < 4; ++p) ebm[t + 256 * p] = 0u;
  __syncthreads();
  if (t < 4) {
    const int r = rep * 1024 + b * 4 + t;
#pragma unroll 1
    for (int p = 0; p < 32; ++p) {
      const int ix = selws[r * 32 + p];
      ebm[t * 256 + (ix >> 5)] |= (1u << (ix & 31));
    }
  }
  __syncthreads();

  const size_t obase = (size_t)grp * ROWN;
#pragma unroll
  for (int j = 0; j < 8; ++j) {
    const int n = s * 2048 + t + 256 * j;
    float4 v;
    v.x = ((ebm[0 * 256 + (n >> 5)] >> (n & 31)) & 1u) ? 1.0f : 0.0f;
    v.y = ((ebm[1 * 256 + (n >> 5)] >> (n & 31)) & 1u) ? 1.0f : 0.0f;
    v.z = ((ebm[2 * 256 + (n >> 5)] >> (n & 31)) & 1u) ? 1.0f : 0.0f;
    v.w = ((ebm[3 * 256 + (n >> 5)] >> (n & 31)) & 1u) ? 1.0f : 0.0f;
    out4[obase + (size_t)n] = v;
  }
}

extern "C" void kernel_launch(void* const* d_in, const int* in_sizes, int n_in,
                              void* d_out, int out_size, void* d_ws, size_t ws_size,
                              hipStream_t stream) {
  const void* scores = d_in[0];      // dtype autodetected in-kernel
  int* selws = (int*)d_ws;           // 2048 rows x 32 ints = 256 KB
  topk_row<<<dim3(2048), dim3(TPB), 0, stream>>>(scores, selws);
  expand_out<<<dim3(2048), dim3(TPB), 0, stream>>>(selws, (float4*)d_out);
}

// Round 7
// 243.403 us; speedup vs baseline: 1.6953x; 1.0413x over previous
//
#include <hip/hip_runtime.h>

#define TPB 256
#define ROWN 8192
#define CMAX 1024   // per-row candidate cap (r12-r18 proven never hit)
#define EPS_TINY 1.1754943508222875e-38f   // np.finfo(np.float32).tiny

__device__ __forceinline__ unsigned rotl32(unsigned x, int r) {
  return (x << r) | (x >> (32 - r));
}

// threefry2x32, key (0,42), partitionable counters: ctr=(0,idx), bits = x0^x1.
// Verified on-device (r11 decode; r12-r18 absmax 0.0).
__device__ __forceinline__ unsigned tf_pxor(unsigned idx) {
  const unsigned ks0 = 0u, ks1 = 42u, ks2 = 0x1BD11BDAu ^ 0u ^ 42u;
  unsigned x0 = ks0;
  unsigned x1 = idx + ks1;
#define TF4(a,b,cc,d) \
  x0 += x1; x1 = rotl32(x1,(a));  x1 ^= x0; \
  x0 += x1; x1 = rotl32(x1,(b));  x1 ^= x0; \
  x0 += x1; x1 = rotl32(x1,(cc)); x1 ^= x0; \
  x0 += x1; x1 = rotl32(x1,(d));  x1 ^= x0;
  TF4(13,15,26,6)   x0 += ks1; x1 += ks2 + 1u;
  TF4(17,29,16,24)  x0 += ks2; x1 += ks0 + 2u;
  TF4(13,15,26,6)   x0 += ks0; x1 += ks1 + 3u;
  TF4(17,29,16,24)  x0 += ks1; x1 += ks2 + 4u;
  TF4(13,15,26,6)   x0 += ks2; x1 += ks0 + 5u;
#undef TF4
  return x0 ^ x1;
}

// EXACT jax gumbel (precise ocml logf) — candidates only, bit-exact.
__device__ __forceinline__ float gumbel_of(unsigned idx) {
  const unsigned bits = tf_pxor(idx);
  float u = __uint_as_float((bits >> 9) | 0x3f800000u) - 1.0f;
  u = u + EPS_TINY;
  u = fmaxf(EPS_TINY, u);
  return -logf(-logf(u));
}

// APPROX gumbel for the filter pass: |err| <= ~2e-4 (proven r15-r18).
__device__ __forceinline__ float approx_gumbel(unsigned bits) {
  float u = __uint_as_float((bits >> 9) | 0x3f800000u) - 1.0f;
  u = u + EPS_TINY;
  u = fmaxf(EPS_TINY, u);
  float t;
  if (u >= 0.75f) {
    const float v = 1.0f - u;   // exact (Sterbenz)
    t = v * (1.0f + v * (0.5f + v * (0.33333334f + v * (0.25f + v * 0.2f))));
  } else {
    t = -0.69314718f * __log2f(u);
  }
  return -0.69314718f * __log2f(t);
}

// Monotone 16-bit sort key of bf16-truncated float: x<=y  =>  key(x)<=key(y).
// (bf16 truncation + sign-flip map; f is finite here: |score|<=16, gumbel
// in (-5, ~30), no NaN/inf.)
__device__ __forceinline__ unsigned key16_of(float x) {
  const unsigned b = __float_as_uint(x) >> 16;
  return (b & 0x8000u) ? (0xFFFFu & ~b) : (b | 0x8000u);
}

// =====================================================================
// Fused kernel: one block per (rep, b, e) ROW. grid=2048, 256 thr.
// r6 structure + ONE change: filter values held as packed 16-bit sort
// keys fb[16] (2/reg) instead of f[32] — halves the pinned live set so
// __launch_bounds__(256,8) fits 64 unified regs WITHOUT spilling
// (r1's (256,8) spilled 39MB because f[32] couldn't fit).
// Safety (provable, not empirical): key map g is monotone, so
// g(f)>g(lo) => f>lo; bisect invariant count>=33 still gives
// lo < f*_(33), theta=lo-2.34 keeps the full proven margin. Compact
// uses g(f) >= g(theta) so quantization only ADDS boundary candidates
// (superset, ~+4). Candidates still get bit-exact gumbel_of cf.
// Dynamics/selection identical to r6 (absmax 0.0 proven).
// =====================================================================
__global__ __launch_bounds__(TPB, 8)
void topk_row(const void* __restrict__ scores_raw, int* __restrict__ selws) {
  const int t    = threadIdx.x;
  const int lane = t & 63;
  const int wave = t >> 6;

  // XCD grouping: all 8 rows (4e x 2rep) of input panel b land on one XCD.
  const int i   = blockIdx.x;       // 0..2047
  const int xcd = i & 7;
  const int k   = i >> 3;           // 0..255
  const int e   = k & 3;
  const int q   = k >> 2;           // 0..63
  const int b   = xcd * 32 + (q & 31);
  const int rep = q >> 5;
  const int r   = rep * 1024 + b * 4 + e;
  const unsigned gbase = (unsigned)r * (unsigned)ROWN;

  __shared__ int   candIdx[CMAX];     // 4 KB
  __shared__ float redM[4];
  __shared__ float redZ[4];
  __shared__ int   wtot[13][4];
  __shared__ float bV[2][4];
  __shared__ int   bI[2][4];
  __shared__ int   f32flag;

  // ---- input dtype autodetect (4 KB prefix; proven r11-r18) ----
  if (t == 0) f32flag = 0;
  __syncthreads();
  {
    const unsigned* w = (const unsigned*)scores_raw;
    bool bad = false;
#pragma unroll
    for (int p = 0; p < 4; ++p) {
      const unsigned x = w[t + 256 * p];
      const float flo = __uint_as_float((x & 0xFFFFu) << 16);
      const float fhi = __uint_as_float(x & 0xFFFF0000u);
      if (!(fabsf(flo) <= 16.0f) || !(fabsf(fhi) <= 16.0f)) bad = true;
    }
    if (bad) f32flag = 1;
  }
  __syncthreads();
  const bool in_f32 = (f32flag != 0);

  // ================= phase 1: gen -> theta -> compact (single row) ======
  const size_t ebase0 = ((size_t)b * ROWN + (size_t)t) * 4 + (size_t)e;
  unsigned fb[16];                    // 32 filter keys, 2 per reg
  float m = -3.4e38f;
  if (in_f32) {
    const float* sp = (const float*)scores_raw;
#pragma unroll
    for (int j = 0; j < 32; ++j) {
      const float fj = sp[ebase0 + (size_t)(256 * j) * 4]
                     + approx_gumbel(tf_pxor(gbase + (unsigned)(t + 256 * j)));
      m = fmaxf(m, fj);
      const unsigned kk = key16_of(fj);
      if (j & 1) fb[j >> 1] |= kk << 16; else fb[j >> 1] = kk;
    }
  } else {
    const unsigned short* sp = (const unsigned short*)scores_raw;
#pragma unroll
    for (int j = 0; j < 32; ++j) {
      const float fj = __uint_as_float(((unsigned)sp[ebase0 + (size_t)(256 * j) * 4]) << 16)
                     + approx_gumbel(tf_pxor(gbase + (unsigned)(t + 256 * j)));
      m = fmaxf(m, fj);
      const unsigned kk = key16_of(fj);
      if (j & 1) fb[j >> 1] |= kk << 16; else fb[j >> 1] = kk;
    }
  }

  // block max (f32, computed before packing)
#pragma unroll
  for (int off = 32; off >= 1; off >>= 1) m = fmaxf(m, __shfl_xor(m, off));
  if (lane == 0) redM[wave] = m;
  __syncthreads();
  m = fmaxf(fmaxf(redM[0], redM[1]), fmaxf(redM[2], redM[3]));

  // bisect theta33 (12 iters, f32 mids, counts in key domain)
  float lo = m - 25.0f, hi = m;
#pragma unroll 1
  for (int itb = 0; itb < 12; ++itb) {
    const float mid = 0.5f * (lo + hi);
    const unsigned kmid = key16_of(mid);
    int c = 0;
#pragma unroll
    for (int h = 0; h < 16; ++h) {
      c += ((fb[h] & 0xFFFFu) > kmid) ? 1 : 0;
      c += ((fb[h] >> 16) > kmid) ? 1 : 0;
    }
#pragma unroll
    for (int off = 32; off >= 1; off >>= 1) c += __shfl_xor(c, off);
    if (lane == 0) wtot[itb][wave] = c;
    __syncthreads();
    const int tot = wtot[itb][0] + wtot[itb][1] + wtot[itb][2] + wtot[itb][3];
    if (tot >= 33) lo = mid; else hi = mid;
  }
  const float theta = lo - 2.34f;          // lo < f*_(33) proven via monotone key
  const unsigned ktheta = key16_of(theta); // compact predicate: key >= ktheta

  // compact candidate indices (deterministic prefix order, >= for superset)
  int cj = 0;
#pragma unroll
  for (int h = 0; h < 16; ++h) {
    cj += ((fb[h] & 0xFFFFu) >= ktheta) ? 1 : 0;
    cj += ((fb[h] >> 16) >= ktheta) ? 1 : 0;
  }
  int incv = cj;
#pragma unroll
  for (int off = 1; off < 64; off <<= 1) {
    const int v = __shfl_up(incv, off);
    if (lane >= off) incv += v;
  }
  if (lane == 63) wtot[12][wave] = incv;
  __syncthreads();
  int base = 0;
  for (int w = 0; w < wave; ++w) base += wtot[12][w];
  int cnt = wtot[12][0] + wtot[12][1] + wtot[12][2] + wtot[12][3];
  if (cnt > CMAX) cnt = CMAX;
  int o = base + incv - cj;
#pragma unroll
  for (int j = 0; j < 32; ++j) {
    const unsigned kj = (j & 1) ? (fb[j >> 1] >> 16) : (fb[j >> 1] & 0xFFFFu);
    if (kj >= ktheta) {
      if (o < CMAX) candIdx[o] = t + 256 * j;
      ++o;
    }
  }
  __syncthreads();   // candIdx visible to whole block

  // ================= phase 2: block-wide dynamics (4 chunks of 256) =====
  float cfr[4], khr[4];
  int   idxr[4];
#pragma unroll
  for (int p = 0; p < 4; ++p) {
    cfr[p] = -3.0e38f; khr[p] = -3.0e38f; idxr[p] = 0x7FFFFFFF;
    if (256 * p < cnt) {               // block-uniform chunk skip
      const int ci = t + 256 * p;
      if (ci < cnt) {
        const int n = candIdx[ci];
        const size_t ei = ((size_t)b * ROWN + (size_t)n) * 4 + (size_t)e;
        float sc;
        if (in_f32) sc = ((const float*)scores_raw)[ei];
        else sc = __uint_as_float(((unsigned)((const unsigned short*)scores_raw)[ei]) << 16);
        cfr[p] = sc + gumbel_of(gbase + (unsigned)n);   // bit-exact
        khr[p] = 0.0f;
        idxr[p] = n;
      }
    }
  }

  // 32 dynamics iterations; fast-math branchless body (r6, absmax 0.0).
#pragma unroll 1
  for (int it = 0; it < 32; ++it) {
    float m2 = -3.4e38f;
#pragma unroll
    for (int p = 0; p < 4; ++p)
      if (256 * p < cnt) m2 = fmaxf(m2, cfr[p]);
#pragma unroll
    for (int off = 32; off >= 1; off >>= 1) m2 = fmaxf(m2, __shfl_xor(m2, off));
    if (lane == 0) redM[wave] = m2;
    __syncthreads();
    m2 = fmaxf(fmaxf(redM[0], redM[1]), fmaxf(redM[2], redM[3]));

    float ek[4];
    float Z = 0.0f;
#pragma unroll
    for (int p = 0; p < 4; ++p) {
      float ev = 0.0f;
      if (256 * p < cnt) {
        // filler cfr=-3e38: (cfr-m2)*10 -> -inf -> ev = 0 (exact no-op)
        ev = __expf((cfr[p] - m2) * 10.0f);
        Z += ev;
      }
      ek[p] = ev;
    }
#pragma unroll
    for (int off = 32; off >= 1; off >>= 1) Z += __shfl_xor(Z, off);
    if (lane == 0) redZ[wave] = Z;
    __syncthreads();
    Z = (redZ[0] + redZ[1]) + (redZ[2] + redZ[3]);   // fixed deterministic order

    const float rz = __builtin_amdgcn_rcpf(Z);       // Z in [1, cnt]; rel err ~1e-7
#pragma unroll
    for (int p = 0; p < 4; ++p) {
      if (256 * p < cnt) {
        const float pp = ek[p] * rz;                 // 0 for inactive lanes
        khr[p] += pp;                                // += 0 is bitwise no-op
        cfr[p] += __logf(fmaxf(1.0f - pp, EPS_TINY));
      }
    }
  }

  // top-32 of khot, lowest-n tie-break, block-wide (double-buffered slots)
#pragma unroll 1
  for (int pass = 0; pass < 32; ++pass) {
    float bv = -3.4e38f; int bi = 0x7FFFFFFF;
#pragma unroll
    for (int p = 0; p < 4; ++p) {
      if (256 * p < cnt) {
        const float v = khr[p]; const int ix = idxr[p];
        if (v > bv || (v == bv && ix < bi)) { bv = v; bi = ix; }
      }
    }
#pragma unroll
    for (int off = 32; off >= 1; off >>= 1) {
      const float ov = __shfl_xor(bv, off);
      const int   oi = __shfl_xor(bi, off);
      if (ov > bv || (ov == bv && oi < bi)) { bv = ov; bi = oi; }
    }
    if (lane == 0) { bV[pass & 1][wave] = bv; bI[pass & 1][wave] = bi; }
    __syncthreads();
#pragma unroll
    for (int w = 0; w < 4; ++w) {
      const float ov = bV[pass & 1][w]; const int oi = bI[pass & 1][w];
      if (ov > bv || (ov == bv && oi < bi)) { bv = ov; bi = oi; }
    }
    if (t == 0) selws[r * 32 + pass] = bi;
#pragma unroll
    for (int p = 0; p < 4; ++p)
      if (256 * p < cnt && idxr[p] == bi) khr[p] = -3.0e38f;
  }
}

// =====================================================================
// Kernel 2: bitmap expand -> coalesced float4 slab (unchanged, proven).
// =====================================================================
__global__ __launch_bounds__(TPB)
void expand_out(const int* __restrict__ selws, float4* __restrict__ out4) {
  const int t   = threadIdx.x;
  const int blk = blockIdx.x;        // 0..2047
  const int grp = blk >> 2;          // rep*256 + b
  const int s   = blk & 3;           // n-slice of 2048
  const int rep = grp >> 8;
  const int b   = grp & 255;

  __shared__ unsigned ebm[4 * 256];  // 4 e-planes x 8192 bits
#pragma unroll
  for (int p = 0; p < 4; ++p) ebm[t + 256 * p] = 0u;
  __syncthreads();
  if (t < 4) {
    const int r = rep * 1024 + b * 4 + t;
#pragma unroll 1
    for (int p = 0; p < 32; ++p) {
      const int ix = selws[r * 32 + p];
      ebm[t * 256 + (ix >> 5)] |= (1u << (ix & 31));
    }
  }
  __syncthreads();

  const size_t obase = (size_t)grp * ROWN;
#pragma unroll
  for (int j = 0; j < 8; ++j) {
    const int n = s * 2048 + t + 256 * j;
    float4 v;
    v.x = ((ebm[0 * 256 + (n >> 5)] >> (n & 31)) & 1u) ? 1.0f : 0.0f;
    v.y = ((ebm[1 * 256 + (n >> 5)] >> (n & 31)) & 1u) ? 1.0f : 0.0f;
    v.z = ((ebm[2 * 256 + (n >> 5)] >> (n & 31)) & 1u) ? 1.0f : 0.0f;
    v.w = ((ebm[3 * 256 + (n >> 5)] >> (n & 31)) & 1u) ? 1.0f : 0.0f;
    out4[obase + (size_t)n] = v;
  }
}

extern "C" void kernel_launch(void* const* d_in, const int* in_sizes, int n_in,
                              void* d_out, int out_size, void* d_ws, size_t ws_size,
                              hipStream_t stream) {
  const void* scores = d_in[0];      // dtype autodetected in-kernel
  int* selws = (int*)d_ws;           // 2048 rows x 32 ints = 256 KB
  topk_row<<<dim3(2048), dim3(TPB), 0, stream>>>(scores, selws);
  expand_out<<<dim3(2048), dim3(TPB), 0, stream>>>(selws, (float4*)d_out);
}